// Round 17
// baseline (398.631 us; speedup 1.0000x reference)
//
#include <hip/hip_runtime.h>
#include <math.h>

#define BS 32
#define N 2048
#define ROWS (BS * N)
#define IN 128
#define HID 64
#define K_CAP 80
#define EPS 1e-5f
#define ALPHA 0.1f

typedef float fx4 __attribute__((ext_vector_type(4)));  // nontemporal-compatible

// ---------------------------------------------------------------------------
// Kernel 1: build ELL adjacency + dinv. (measured r10: ~91 us = HBM floor)
// ---------------------------------------------------------------------------
__global__ __launch_bounds__(256) void k_build(const float* __restrict__ adj,
                                               int* __restrict__ ell,
                                               int* __restrict__ cnt,
                                               float* __restrict__ dinv) {
    int lane = threadIdx.x & 63;
    int row  = blockIdx.x * 4 + (threadIdx.x >> 6);
    const fx4* arow = (const fx4*)(adj + (size_t)row * N);
    int* erow = ell + (size_t)row * K_CAP;
    int base = 0;
#pragma unroll
    for (int it = 0; it < N / 256; it++) {
        fx4 f = __builtin_nontemporal_load(&arow[it * 64 + lane]);
#pragma unroll
        for (int k = 0; k < 4; k++) {
            float v = f[k];
            unsigned long long m = __ballot(v != 0.0f);
            if (v != 0.0f) {
                int pos = base + __popcll(m & ((1ull << lane) - 1ull));
                if (pos < K_CAP) erow[pos] = it * 256 + lane * 4 + k;
            }
            base += __popcll(m);
        }
    }
    if (lane == 0) {
        cnt[row]  = base < K_CAP ? base : K_CAP;
        dinv[row] = rsqrtf((float)base + 1.0f);
    }
}

// ---------------------------------------------------------------------------
// Kernel 2: h = x @ proj_w + proj_b, fused with layer-0 LN+ReLU -> z0 (f32).
// ---------------------------------------------------------------------------
__global__ __launch_bounds__(256) void k_proj_ln(const float* __restrict__ x,
                                                 const float* __restrict__ w,
                                                 const float* __restrict__ b,
                                                 const float* __restrict__ g0,
                                                 const float* __restrict__ b0,
                                                 float* __restrict__ h,
                                                 float* __restrict__ z0) {
    __shared__ float sw[IN * HID];
    __shared__ float sx[4][IN];
    int tx = threadIdx.x;
    for (int i = tx; i < IN * HID; i += 256) sw[i] = w[i];
    int row0 = blockIdx.x * 4;
    if (tx < 128) {
        float4 v = *(const float4*)(x + (size_t)(row0 + (tx >> 5)) * IN + (tx & 31) * 4);
        *(float4*)&sx[tx >> 5][(tx & 31) * 4] = v;
    }
    __syncthreads();
    int c = tx & 63, r = tx >> 6;
    float acc = b[c];
#pragma unroll
    for (int k = 0; k < IN; k += 4) {
        float4 xa = *(const float4*)&sx[r][k];
        acc += xa.x * sw[(k + 0) * HID + c];
        acc += xa.y * sw[(k + 1) * HID + c];
        acc += xa.z * sw[(k + 2) * HID + c];
        acc += xa.w * sw[(k + 3) * HID + c];
    }
    size_t idx = (size_t)(row0 + r) * HID + c;
    h[idx] = acc;
    float sum = acc;
    for (int o = 32; o >= 1; o >>= 1) sum += __shfl_xor(sum, o);
    float mu = sum * (1.0f / 64.0f);
    float d  = acc - mu;
    float vs = d * d;
    for (int o = 32; o >= 1; o >>= 1) vs += __shfl_xor(vs, o);
    float rr = rsqrtf(vs * (1.0f / 64.0f) + EPS);
    float zz = d * rr * g0[c] + b0[c];
    z0[idx] = zz > 0.0f ? zz : 0.0f;
}

// ---------------------------------------------------------------------------
// Kernel 3 (per layer). VALU-bound (r15 counters: HBM 4%, conflicts 0).
// This round: z in f32 -- removes all bf16<->f32 conversion VALU from the
// hot loop (the r9 bf16 change was a measured null on bytes; conversions
// are pure cost at the actual bottleneck). Keeps r16's launch_bounds(256,8),
// 32-bit addressing, deferred zi/di.
// ---------------------------------------------------------------------------
__global__ __launch_bounds__(256, 8) void k_layer(
    float* __restrict__ h, const float* __restrict__ z_in,
    float* __restrict__ z_out,
    const int* __restrict__ ell, const int* __restrict__ cnt,
    const float* __restrict__ dinv, const float* __restrict__ w,
    const float* __restrict__ g_next, const float* __restrict__ b_next,
    float beta, int is_last,
    const float* __restrict__ head_w, const float* __restrict__ head_b,
    float* __restrict__ out) {
    __shared__ float ss[16][HID];
    int tx = threadIdx.x;
    int lane = tx & 63, wid = tx >> 6;
    int p = lane & 15, q = lane >> 4;

    int bid = blockIdx.x;
    int swz = (bid & 7) * (int)(gridDim.x >> 3) + (bid >> 3);
    int row0 = swz * 16 + wid * 4;
    int jbase = row0 & ~(N - 1);
    const float4* zb4 = (const float4*)z_in + (unsigned)jbase * 16u;  // batch slab
    const float4* zr4 = (const float4*)z_in;                          // global

    // ---- minimal preload: nn / myidx / myw only ----
    int   nn[4];
    int   myidx[4];
    float myw[4];
#pragma unroll
    for (int rr = 0; rr < 4; rr++) {
        int row = row0 + rr;
        nn[rr] = cnt[row];
        myidx[rr] = 0; myw[rr] = 0.0f;
        if (lane < nn[rr]) {
            myidx[rr] = ell[(unsigned)row * K_CAP + lane];
            myw[rr]   = dinv[jbase + myidx[rr]];
        }
    }
    int ntm = 0;
#pragma unroll
    for (int rr = 0; rr < 4; rr++) {
        int nm = nn[rr] < 64 ? nn[rr] : 64;
        nm = (nm + 3) & ~3;
        ntm = nm > ntm ? nm : ntm;   // wave-uniform
    }

    // ---- interleaved gather (4 rows), f32 features, 32-bit offsets ----
    float4 acc[4];
#pragma unroll
    for (int rr = 0; rr < 4; rr++) acc[rr] = make_float4(0.f, 0.f, 0.f, 0.f);
    for (int t = q; t < ntm; t += 4) {
#pragma unroll
        for (int rr = 0; rr < 4; rr++) {
            int   j  = __shfl(myidx[rr], t);   // all 64 lanes active
            float wj = __shfl(myw[rr], t);     // t >= nn[rr] -> 0
            float4 zj = zb4[(unsigned)(j * 16 + p)];
            acc[rr].x += wj * zj.x; acc[rr].y += wj * zj.y;
            acc[rr].z += wj * zj.z; acc[rr].w += wj * zj.w;
        }
    }
#pragma unroll
    for (int rr = 0; rr < 4; rr++) {          // rare deg>64 tail, no shfl
        for (int t = 64 + q; t < nn[rr]; t += 4) {
            int   j  = jbase + ell[(unsigned)(row0 + rr) * K_CAP + t];
            float wj = dinv[j];
            float4 zj = zr4[(unsigned)(j * 16 + p)];
            acc[rr].x += wj * zj.x; acc[rr].y += wj * zj.y;
            acc[rr].z += wj * zj.z; acc[rr].w += wj * zj.w;
        }
    }

    // ---- merge groups; deferred zi/di load ----
    const float c1 = 1.0f - ALPHA;
#pragma unroll
    for (int rr = 0; rr < 4; rr++) {
        float4 a = acc[rr];
        a.x += __shfl_xor(a.x, 16); a.y += __shfl_xor(a.y, 16);
        a.z += __shfl_xor(a.z, 16); a.w += __shfl_xor(a.w, 16);
        a.x += __shfl_xor(a.x, 32); a.y += __shfl_xor(a.y, 32);
        a.z += __shfl_xor(a.z, 32); a.w += __shfl_xor(a.w, 32);
        int row = row0 + rr;
        float dd = dinv[row];
        float4 zi = zr4[(unsigned)(row * 16 + p)];
        float4 s4;
        s4.x = c1 * dd * (a.x + dd * zi.x) + ALPHA * zi.x;
        s4.y = c1 * dd * (a.y + dd * zi.y) + ALPHA * zi.y;
        s4.z = c1 * dd * (a.z + dd * zi.z) + ALPHA * zi.z;
        s4.w = c1 * dd * (a.w + dd * zi.w) + ALPHA * zi.w;
        if (q == 0) *(float4*)&ss[wid * 4 + rr][4 * p] = s4;
    }
    // ss is wave-private (indexed by wid); wave-internal LDS write->read is
    // ordered by lgkmcnt -> no __syncthreads anywhere.

    // ---- matvec, k-chunk outer, W from global (L1), 32-bit offsets ----
    float mv[4] = {0.f, 0.f, 0.f, 0.f};
#pragma unroll 4
    for (int k = 0; k < HID; k += 4) {
        float w0 = w[(unsigned)((k + 0) * HID + lane)];
        float w1 = w[(unsigned)((k + 1) * HID + lane)];
        float w2 = w[(unsigned)((k + 2) * HID + lane)];
        float w3 = w[(unsigned)((k + 3) * HID + lane)];
#pragma unroll
        for (int rr = 0; rr < 4; rr++) {
            float4 sk = *(const float4*)&ss[wid * 4 + rr][k];
            mv[rr] += sk.x * w0 + sk.y * w1 + sk.z * w2 + sk.w * w3;
        }
    }

    // ---- residual + LN/head per row ----
#pragma unroll
    for (int rr = 0; rr < 4; rr++) {
        int row = row0 + rr;
        float s_c = ss[wid * 4 + rr][lane];
        unsigned idx = (unsigned)(row * HID + lane);
        float hn = __builtin_nontemporal_load(h + idx) +
                   (1.0f - beta) * s_c + beta * mv[rr];
        if (!is_last) {
            __builtin_nontemporal_store(hn, h + idx);
            float sum = hn;
            for (int o = 32; o >= 1; o >>= 1) sum += __shfl_xor(sum, o);
            float mu = sum * (1.0f / 64.0f);
            float d  = hn - mu;
            float vs = d * d;
            for (int o = 32; o >= 1; o >>= 1) vs += __shfl_xor(vs, o);
            float rv = rsqrtf(vs * (1.0f / 64.0f) + EPS);
            float zz = d * rv * g_next[lane] + b_next[lane];
            z_out[idx] = zz > 0.0f ? zz : 0.0f;
        } else {
            float v = hn * head_w[lane];
            for (int o = 32; o >= 1; o >>= 1) v += __shfl_xor(v, o);
            if (lane == 0) out[row] = v + head_b[0];
        }
    }
}

extern "C" void kernel_launch(void* const* d_in, const int* in_sizes, int n_in,
                              void* d_out, int out_size, void* d_ws, size_t ws_size,
                              hipStream_t stream) {
    const float* x      = (const float*)d_in[0];
    const float* adj    = (const float*)d_in[1];
    const float* proj_w = (const float*)d_in[2];
    const float* proj_b = (const float*)d_in[3];
    const float* ln_g   = (const float*)d_in[4];
    const float* ln_b   = (const float*)d_in[5];
    const float* conv_w = (const float*)d_in[6];
    const float* head_w = (const float*)d_in[7];
    const float* head_b = (const float*)d_in[8];
    float* out = (float*)d_out;

    float* h    = (float*)d_ws;                  // ROWS*HID f32
    float* za   = h + (size_t)ROWS * HID;        // ROWS*HID f32
    float* zb   = za + (size_t)ROWS * HID;       // ROWS*HID f32
    float* dinv = zb + (size_t)ROWS * HID;       // ROWS
    int*   cnt  = (int*)(dinv + ROWS);           // ROWS
    int*   ell  = cnt + ROWS;                    // ROWS*K_CAP

    dim3 blk(256);

    k_build<<<dim3(ROWS / 4), blk, 0, stream>>>(adj, ell, cnt, dinv);
    k_proj_ln<<<dim3(ROWS / 4), blk, 0, stream>>>(x, proj_w, proj_b, ln_g, ln_b, h, za);

    float* zin = za;
    float* zout = zb;
    for (int i = 0; i < 4; i++) {
        float beta = (float)log(1.0 / (double)(i + 1) + 1.0);
        int last = (i == 3);
        int gi = (i + 1) < 3 ? (i + 1) : 3;
        k_layer<<<dim3(ROWS / 16), blk, 0, stream>>>(h, zin, zout, ell, cnt, dinv,
                                                     conv_w + (size_t)i * HID * HID,
                                                     ln_g + gi * HID, ln_b + gi * HID,
                                                     beta, last, head_w, head_b, out);
        float* t = zin; zin = zout; zout = t;
    }
}

// Round 18
// 364.742 us; speedup vs baseline: 1.0929x; 1.0929x over previous
//
#include <hip/hip_runtime.h>
#include <math.h>

#define BS 32
#define N 2048
#define ROWS (BS * N)
#define IN 128
#define HID 64
#define K_CAP 80
#define EPS 1e-5f
#define ALPHA 0.1f

typedef float fx4 __attribute__((ext_vector_type(4)));  // nontemporal-compatible

__device__ __forceinline__ float bf2f(unsigned short u) {
    union { float f; unsigned v; } x; x.v = ((unsigned)u) << 16; return x.f;
}
__device__ __forceinline__ unsigned short f2bf(float f) {
    union { float f; unsigned v; } x; x.f = f;
    unsigned r = x.v + 0x7fff + ((x.v >> 16) & 1);  // round-to-nearest-even
    return (unsigned short)(r >> 16);
}

// ---------------------------------------------------------------------------
// Kernel 1: build ELL adjacency + dinv. (measured r10: ~91 us = HBM floor)
// ---------------------------------------------------------------------------
__global__ __launch_bounds__(256) void k_build(const float* __restrict__ adj,
                                               int* __restrict__ ell,
                                               int* __restrict__ cnt,
                                               float* __restrict__ dinv) {
    int lane = threadIdx.x & 63;
    int row  = blockIdx.x * 4 + (threadIdx.x >> 6);
    const fx4* arow = (const fx4*)(adj + (size_t)row * N);
    int* erow = ell + (size_t)row * K_CAP;
    int base = 0;
#pragma unroll
    for (int it = 0; it < N / 256; it++) {
        fx4 f = __builtin_nontemporal_load(&arow[it * 64 + lane]);
#pragma unroll
        for (int k = 0; k < 4; k++) {
            float v = f[k];
            unsigned long long m = __ballot(v != 0.0f);
            if (v != 0.0f) {
                int pos = base + __popcll(m & ((1ull << lane) - 1ull));
                if (pos < K_CAP) erow[pos] = it * 256 + lane * 4 + k;
            }
            base += __popcll(m);
        }
    }
    if (lane == 0) {
        cnt[row]  = base < K_CAP ? base : K_CAP;
        dinv[row] = rsqrtf((float)base + 1.0f);
    }
}

// ---------------------------------------------------------------------------
// Kernel 2: h = x @ proj_w + proj_b, fused with layer-0 LN+ReLU -> z0 (bf16).
// ---------------------------------------------------------------------------
__global__ __launch_bounds__(256) void k_proj_ln(const float* __restrict__ x,
                                                 const float* __restrict__ w,
                                                 const float* __restrict__ b,
                                                 const float* __restrict__ g0,
                                                 const float* __restrict__ b0,
                                                 float* __restrict__ h,
                                                 unsigned short* __restrict__ z0) {
    __shared__ float sw[IN * HID];
    __shared__ float sx[4][IN];
    int tx = threadIdx.x;
    for (int i = tx; i < IN * HID; i += 256) sw[i] = w[i];
    int row0 = blockIdx.x * 4;
    if (tx < 128) {
        float4 v = *(const float4*)(x + (size_t)(row0 + (tx >> 5)) * IN + (tx & 31) * 4);
        *(float4*)&sx[tx >> 5][(tx & 31) * 4] = v;
    }
    __syncthreads();
    int c = tx & 63, r = tx >> 6;
    float acc = b[c];
#pragma unroll
    for (int k = 0; k < IN; k += 4) {
        float4 xa = *(const float4*)&sx[r][k];
        acc += xa.x * sw[(k + 0) * HID + c];
        acc += xa.y * sw[(k + 1) * HID + c];
        acc += xa.z * sw[(k + 2) * HID + c];
        acc += xa.w * sw[(k + 3) * HID + c];
    }
    size_t idx = (size_t)(row0 + r) * HID + c;
    h[idx] = acc;
    float sum = acc;
    for (int o = 32; o >= 1; o >>= 1) sum += __shfl_xor(sum, o);
    float mu = sum * (1.0f / 64.0f);
    float d  = acc - mu;
    float vs = d * d;
    for (int o = 32; o >= 1; o >>= 1) vs += __shfl_xor(vs, o);
    float rr = rsqrtf(vs * (1.0f / 64.0f) + EPS);
    float zz = d * rr * g0[c] + b0[c];
    z0[idx] = f2bf(zz > 0.0f ? zz : 0.0f);
}

// ---------------------------------------------------------------------------
// Kernel 3 (per layer). r16 base (bf16 z, launch_bounds(256,8), 32-bit
// addressing, deferred zi/di -- measured 365us total) + ONE change:
// (weight,index) packed in a single dword. j < 2048 fits in the f32
// weight's low 11 mantissa bits (truncation rel-err ~1e-4):
//   pk = (bits(w) & 0xFFFFF800) | j
// Gather does ONE shfl + two ANDs instead of two shfls. Padding lanes hold
// pk = 0 -> wj = +0.0 exactly (zero-contribution invariant kept, and the
// t<nn compare disappears). ds_bpermute count: 56 -> 28 per wave.
// ---------------------------------------------------------------------------
__global__ __launch_bounds__(256, 8) void k_layer(
    float* __restrict__ h, const unsigned short* __restrict__ z_in,
    unsigned short* __restrict__ z_out,
    const int* __restrict__ ell, const int* __restrict__ cnt,
    const float* __restrict__ dinv, const float* __restrict__ w,
    const float* __restrict__ g_next, const float* __restrict__ b_next,
    float beta, int is_last,
    const float* __restrict__ head_w, const float* __restrict__ head_b,
    float* __restrict__ out) {
    __shared__ float ss[16][HID];
    int tx = threadIdx.x;
    int lane = tx & 63, wid = tx >> 6;
    int p = lane & 15, q = lane >> 4;

    int bid = blockIdx.x;
    int swz = (bid & 7) * (int)(gridDim.x >> 3) + (bid >> 3);
    int row0 = swz * 16 + wid * 4;
    int jbase = row0 & ~(N - 1);
    const ushort4* zb4 = (const ushort4*)z_in + (unsigned)jbase * 16u;  // batch slab
    const ushort4* zr4 = (const ushort4*)z_in;                          // global

    // ---- preload: nn + packed (weight|idx) per lane ----
    int nn[4];
    unsigned mypk[4];
#pragma unroll
    for (int rr = 0; rr < 4; rr++) {
        int row = row0 + rr;
        nn[rr] = cnt[row];
        mypk[rr] = 0u;                       // padded lanes: wj=+0.0, j=0
        if (lane < nn[rr]) {
            int j = ell[(unsigned)row * K_CAP + lane];
            union { float f; unsigned v; } u;
            u.f = dinv[jbase + j];
            mypk[rr] = (u.v & 0xFFFFF800u) | (unsigned)j;
        }
    }
    int ntm = 0;
#pragma unroll
    for (int rr = 0; rr < 4; rr++) {
        int nm = nn[rr] < 64 ? nn[rr] : 64;
        nm = (nm + 3) & ~3;
        ntm = nm > ntm ? nm : ntm;   // wave-uniform
    }

    // ---- interleaved gather (4 rows): ONE shfl per (trip,row) ----
    float4 acc[4];
#pragma unroll
    for (int rr = 0; rr < 4; rr++) acc[rr] = make_float4(0.f, 0.f, 0.f, 0.f);
    for (int t = q; t < ntm; t += 4) {
#pragma unroll
        for (int rr = 0; rr < 4; rr++) {
            unsigned v = (unsigned)__shfl((int)mypk[rr], t);  // all lanes active
            int j = (int)(v & 0x7FFu);
            union { unsigned u; float f; } wu; wu.u = v & 0xFFFFF800u;
            float wj = wu.f;                                  // 0 for padding
            ushort4 zu = zb4[(unsigned)(j * 16 + p)];
            acc[rr].x += wj * bf2f(zu.x); acc[rr].y += wj * bf2f(zu.y);
            acc[rr].z += wj * bf2f(zu.z); acc[rr].w += wj * bf2f(zu.w);
        }
    }
#pragma unroll
    for (int rr = 0; rr < 4; rr++) {          // rare deg>64 tail, no shfl
        for (int t = 64 + q; t < nn[rr]; t += 4) {
            int   j  = jbase + ell[(unsigned)(row0 + rr) * K_CAP + t];
            float wj = dinv[j];
            ushort4 zu = zr4[(unsigned)(j * 16 + p)];
            acc[rr].x += wj * bf2f(zu.x); acc[rr].y += wj * bf2f(zu.y);
            acc[rr].z += wj * bf2f(zu.z); acc[rr].w += wj * bf2f(zu.w);
        }
    }

    // ---- merge groups; deferred zi/di load ----
    const float c1 = 1.0f - ALPHA;
#pragma unroll
    for (int rr = 0; rr < 4; rr++) {
        float4 a = acc[rr];
        a.x += __shfl_xor(a.x, 16); a.y += __shfl_xor(a.y, 16);
        a.z += __shfl_xor(a.z, 16); a.w += __shfl_xor(a.w, 16);
        a.x += __shfl_xor(a.x, 32); a.y += __shfl_xor(a.y, 32);
        a.z += __shfl_xor(a.z, 32); a.w += __shfl_xor(a.w, 32);
        int row = row0 + rr;
        float dd = dinv[row];
        ushort4 zu = zr4[(unsigned)(row * 16 + p)];
        float4 zi = make_float4(bf2f(zu.x), bf2f(zu.y), bf2f(zu.z), bf2f(zu.w));
        float4 s4;
        s4.x = c1 * dd * (a.x + dd * zi.x) + ALPHA * zi.x;
        s4.y = c1 * dd * (a.y + dd * zi.y) + ALPHA * zi.y;
        s4.z = c1 * dd * (a.z + dd * zi.z) + ALPHA * zi.z;
        s4.w = c1 * dd * (a.w + dd * zi.w) + ALPHA * zi.w;
        if (q == 0) *(float4*)&ss[wid * 4 + rr][4 * p] = s4;
    }
    // ss is wave-private (indexed by wid); wave-internal LDS write->read is
    // ordered by lgkmcnt -> no __syncthreads anywhere.

    // ---- matvec, k-chunk outer, W from global (L1), 32-bit offsets ----
    float mv[4] = {0.f, 0.f, 0.f, 0.f};
#pragma unroll 4
    for (int k = 0; k < HID; k += 4) {
        float w0 = w[(unsigned)((k + 0) * HID + lane)];
        float w1 = w[(unsigned)((k + 1) * HID + lane)];
        float w2 = w[(unsigned)((k + 2) * HID + lane)];
        float w3 = w[(unsigned)((k + 3) * HID + lane)];
#pragma unroll
        for (int rr = 0; rr < 4; rr++) {
            float4 sk = *(const float4*)&ss[wid * 4 + rr][k];
            mv[rr] += sk.x * w0 + sk.y * w1 + sk.z * w2 + sk.w * w3;
        }
    }

    // ---- residual + LN/head per row ----
#pragma unroll
    for (int rr = 0; rr < 4; rr++) {
        int row = row0 + rr;
        float s_c = ss[wid * 4 + rr][lane];
        unsigned idx = (unsigned)(row * HID + lane);
        float hn = __builtin_nontemporal_load(h + idx) +
                   (1.0f - beta) * s_c + beta * mv[rr];
        if (!is_last) {
            __builtin_nontemporal_store(hn, h + idx);
            float sum = hn;
            for (int o = 32; o >= 1; o >>= 1) sum += __shfl_xor(sum, o);
            float mu = sum * (1.0f / 64.0f);
            float d  = hn - mu;
            float vs = d * d;
            for (int o = 32; o >= 1; o >>= 1) vs += __shfl_xor(vs, o);
            float rv = rsqrtf(vs * (1.0f / 64.0f) + EPS);
            float zz = d * rv * g_next[lane] + b_next[lane];
            z_out[idx] = f2bf(zz > 0.0f ? zz : 0.0f);
        } else {
            float v = hn * head_w[lane];
            for (int o = 32; o >= 1; o >>= 1) v += __shfl_xor(v, o);
            if (lane == 0) out[row] = v + head_b[0];
        }
    }
}

extern "C" void kernel_launch(void* const* d_in, const int* in_sizes, int n_in,
                              void* d_out, int out_size, void* d_ws, size_t ws_size,
                              hipStream_t stream) {
    const float* x      = (const float*)d_in[0];
    const float* adj    = (const float*)d_in[1];
    const float* proj_w = (const float*)d_in[2];
    const float* proj_b = (const float*)d_in[3];
    const float* ln_g   = (const float*)d_in[4];
    const float* ln_b   = (const float*)d_in[5];
    const float* conv_w = (const float*)d_in[6];
    const float* head_w = (const float*)d_in[7];
    const float* head_b = (const float*)d_in[8];
    float* out = (float*)d_out;

    float* h  = (float*)d_ws;                        // ROWS*HID f32
    unsigned short* za = (unsigned short*)(h + (size_t)ROWS * HID);  // bf16
    unsigned short* zb = za + (size_t)ROWS * HID;                    // bf16
    float* dinv = (float*)(zb + (size_t)ROWS * HID); // ROWS
    int*   cnt  = (int*)(dinv + ROWS);               // ROWS
    int*   ell  = cnt + ROWS;                        // ROWS*K_CAP

    dim3 blk(256);

    k_build<<<dim3(ROWS / 4), blk, 0, stream>>>(adj, ell, cnt, dinv);
    k_proj_ln<<<dim3(ROWS / 4), blk, 0, stream>>>(x, proj_w, proj_b, ln_g, ln_b, h, za);

    unsigned short* zin = za;
    unsigned short* zout = zb;
    for (int i = 0; i < 4; i++) {
        float beta = (float)log(1.0 / (double)(i + 1) + 1.0);
        int last = (i == 3);
        int gi = (i + 1) < 3 ? (i + 1) : 3;
        k_layer<<<dim3(ROWS / 16), blk, 0, stream>>>(h, zin, zout, ell, cnt, dinv,
                                                     conv_w + (size_t)i * HID * HID,
                                                     ln_g + gi * HID, ln_b + gi * HID,
                                                     beta, last, head_w, head_b, out);
        unsigned short* t = zin; zin = zout; zout = t;
    }
}